// Round 4
// baseline (234.624 us; speedup 1.0000x reference)
//
#include <hip/hip_runtime.h>
#include <hip/hip_bf16.h>

typedef __attribute__((ext_vector_type(8))) unsigned short ushort8;
typedef __attribute__((ext_vector_type(4))) float f32x4;
typedef __attribute__((ext_vector_type(8))) __bf16 bf16x8;
typedef unsigned int u32_g __attribute__((address_space(1)));
typedef unsigned int u32_l __attribute__((address_space(3)));

__device__ __forceinline__ float bf2f(unsigned short u) {
  union { unsigned u; float f; } v; v.u = ((unsigned)u) << 16; return v.f;
}
__device__ __forceinline__ unsigned short f2bf(float f) {
  union { float f; unsigned u; } v; v.f = f;
  unsigned r = v.u + 0x7FFFu + ((v.u >> 16) & 1u);
  return (unsigned short)(r >> 16);
}
__device__ __forceinline__ f32x4 mfma16(bf16x8 a, bf16x8 b, f32x4 c) {
  return __builtin_amdgcn_mfma_f32_16x16x32_bf16(a, b, c, 0, 0, 0);
}
__device__ __forceinline__ void gload16(const void* g, void* l) {
  __builtin_amdgcn_global_load_lds((const u32_g*)g, (u32_l*)l, 16, 0, 0);
}

// ---------------- weight transpose+cast: W[K][N] fp32 -> WT[row_off+n][k] bf16
__global__ __launch_bounds__(256) void transpose_cast(
    const float* __restrict__ W, unsigned short* __restrict__ WT,
    int K, int N, int ldwt, int row_off)
{
  __shared__ unsigned short t[64 * 80];
  int n0 = blockIdx.x * 64, k0 = blockIdx.y * 64;
  int tid = threadIdx.x;
#pragma unroll
  for (int i = 0; i < 4; i++) {
    int c = tid + 256 * i;
    int r = c >> 4, q = c & 15;
    float4 v = *(const float4*)&W[(size_t)(k0 + r) * N + n0 + q * 4];
    t[(q * 4 + 0) * 80 + r] = f2bf(v.x);
    t[(q * 4 + 1) * 80 + r] = f2bf(v.y);
    t[(q * 4 + 2) * 80 + r] = f2bf(v.z);
    t[(q * 4 + 3) * 80 + r] = f2bf(v.w);
  }
  __syncthreads();
#pragma unroll
  for (int i = 0; i < 2; i++) {
    int c = tid + 256 * i;
    int n = c >> 3, p = c & 7;
    *(ushort8*)&WT[(size_t)(row_off + n0 + n) * ldwt + k0 + p * 8] =
        *(const ushort8*)&t[n * 80 + p * 8];
  }
}

__global__ void biascat_kernel(const float* __restrict__ bq, const float* __restrict__ bk,
                               const float* __restrict__ bv, const float* __restrict__ bg,
                               float* __restrict__ bcat)
{
  int i = blockIdx.x * 256 + threadIdx.x;   // 6144
  float v;
  if (i < 1024) v = bq[i];
  else if (i < 2048) v = bk[i - 1024];
  else if (i < 4096) v = bv[i - 2048];
  else v = bg[i - 4096];
  bcat[i] = v;
}

__global__ void cast_x_kernel(const float* __restrict__ x, unsigned short* __restrict__ xb)
{
  size_t i = (size_t)(blockIdx.x * 256 + threadIdx.x) * 4;
  float4 v = *(const float4*)&x[i];
  unsigned r0 = (unsigned)f2bf(v.x) | ((unsigned)f2bf(v.y) << 16);
  unsigned r1 = (unsigned)f2bf(v.z) | ((unsigned)f2bf(v.w) << 16);
  uint2 o; o.x = r0; o.y = r1;
  *(uint2*)&xb[i] = o;
}

// ---------------- GEMM: dbuf + single barrier + both-sides swizzle
template<int OUT_BF16, int BN>
__global__ __launch_bounds__(256, 2) void gemm_kernel(
    const unsigned short* __restrict__ A, const unsigned short* __restrict__ BT,
    const float* __restrict__ bias, void* __restrict__ Cout,
    int M, int N, int K)
{
  __shared__ unsigned short As[2 * 128 * 64];
  __shared__ unsigned short Bs[2 * BN * 64];
  constexpr int NR = BN / 32;
  int tid = threadIdx.x;
  int wave = tid >> 6, lane = tid & 63;
  int lr = lane & 15, lg = lane >> 4;
  // bijective XCD swizzle (nwg % 8 == 0 for all our grids)
  int gx = gridDim.x;
  int lin = blockIdx.x + gx * blockIdx.y;
  int cpx = (gx * gridDim.y) >> 3;
  int lin2 = (lin & 7) * cpx + (lin >> 3);
  int m0 = (lin2 / gx) * 128, n0 = (lin2 % gx) * BN;
  int wr = (wave >> 1) * 64, wc = (wave & 1) * (BN / 2);
  int srow = tid >> 3, sc8 = tid & 7;
  int ssw = (sc8 ^ (srow & 7)) * 8;          // swizzled source chunk (shorts)
  const unsigned short* ga = &A[(size_t)(m0 + srow) * K + ssw];
  const unsigned short* gb = &BT[(size_t)(n0 + srow) * K + ssw];
  int rsw = lr & 7;                          // read-side chunk XOR
  f32x4 acc[4][NR] = {};

  auto stage = [&](int buf, int k0) {
    char* la = (char*)&As[buf * 128 * 64];
    char* lb = (char*)&Bs[buf * BN * 64];
#pragma unroll
    for (int i = 0; i < 4; i++)
      gload16(ga + (size_t)i * 32 * K + k0, la + (tid + i * 256) * 16);
#pragma unroll
    for (int i = 0; i < NR; i++)
      gload16(gb + (size_t)i * 32 * K + k0, lb + (tid + i * 256) * 16);
  };

  int nk = K >> 6;
  stage(0, 0);
  for (int it = 0; it < nk; it++) {
    __syncthreads();                          // drains stage(it); all waves done reading buf^1
    if (it + 1 < nk) stage((it + 1) & 1, (it + 1) * 64);
    const unsigned short* as = &As[(it & 1) * 128 * 64];
    const unsigned short* bs = &Bs[(it & 1) * BN * 64];
#pragma unroll
    for (int kk = 0; kk < 2; kk++) {
      int csw = ((kk * 4 + lg) ^ rsw) * 8;
      bf16x8 af[4], bfr[NR];
#pragma unroll
      for (int m = 0; m < 4; m++)
        af[m] = *(const bf16x8*)&as[(wr + m * 16 + lr) * 64 + csw];
#pragma unroll
      for (int n = 0; n < NR; n++)
        bfr[n] = *(const bf16x8*)&bs[(wc + n * 16 + lr) * 64 + csw];
#pragma unroll
      for (int m = 0; m < 4; m++)
#pragma unroll
        for (int n = 0; n < NR; n++)
          acc[m][n] = mfma16(af[m], bfr[n], acc[m][n]);
    }
  }
#pragma unroll
  for (int m = 0; m < 4; m++) {
#pragma unroll
    for (int n = 0; n < NR; n++) {
      int col = n0 + wc + n * 16 + lr;
      float bv = bias ? bias[col] : 0.f;
#pragma unroll
      for (int r = 0; r < 4; r++) {
        int row = m0 + wr + m * 16 + lg * 4 + r;
        float v = acc[m][n][r] + bv;
        if (OUT_BF16)
          ((unsigned short*)Cout)[(size_t)row * N + col] = f2bf(v);
        else
          ((float*)Cout)[(size_t)row * N + col] = v;
      }
    }
  }
}

// ---------------- prep: RoPE for q,k -> [BH][S][64] bf16
__global__ __launch_bounds__(256) void prep_qk_kernel(
    const unsigned short* __restrict__ Y,
    unsigned short* __restrict__ qr, unsigned short* __restrict__ kr)
{
  int t = blockIdx.x * 256 + threadIdx.x;  // [bs:4096][h:16][j:32]
  int j = t & 31;
  int h = (t >> 5) & 15;
  int bs = t >> 9;
  int s = bs & 2047;
  int b = bs >> 11;
  float ang = __expf(-0.29710774f * (float)j);   // 10000^(-j/31)
  float th = (float)s * ang;
  float sn, cs;
  __sincosf(th, &sn, &cs);
  const unsigned short* yq = &Y[(size_t)bs * 6144 + h * 64 + 2 * j];
  unsigned qv = *(const unsigned*)yq;
  unsigned kv = *(const unsigned*)(yq + 1024);
  float q0 = bf2f((unsigned short)(qv & 0xffff));
  float q1 = bf2f((unsigned short)(qv >> 16));
  float k0 = bf2f((unsigned short)(kv & 0xffff)) * 0.125f;
  float k1 = bf2f((unsigned short)(kv >> 16)) * 0.125f;
  float qr0 = q0 * cs - q1 * sn, qr1 = q1 * cs + q0 * sn;
  float kr0 = k0 * cs - k1 * sn, kr1 = k1 * cs + k0 * sn;
  size_t o = ((size_t)(b * 16 + h) * 2048 + s) * 64 + 2 * j;
  *(unsigned*)&qr[o] = (unsigned)f2bf(qr0) | ((unsigned)f2bf(qr1) << 16);
  *(unsigned*)&kr[o] = (unsigned)f2bf(kr0) | ((unsigned)f2bf(kr1) << 16);
}

// ---------------- prep: v transpose -> vT[BH][128][2048] bf16
__global__ __launch_bounds__(256) void prep_v_kernel(
    const unsigned short* __restrict__ Y, unsigned short* __restrict__ vT)
{
  __shared__ unsigned short t[128 * 80];
  int s0 = blockIdx.x * 64;
  int bh = blockIdx.y;
  int b = bh >> 4, h = bh & 15;
  int tid = threadIdx.x;
#pragma unroll
  for (int i = 0; i < 4; i++) {
    int c = tid + 256 * i;
    int r = c >> 4, p = c & 15;
    ushort8 v = *(const ushort8*)&Y[(size_t)(b * 2048 + s0 + r) * 6144 + 2048 + h * 128 + p * 8];
#pragma unroll
    for (int e = 0; e < 8; e++) t[(p * 8 + e) * 80 + r] = v[e];
  }
  __syncthreads();
#pragma unroll
  for (int i = 0; i < 4; i++) {
    int c = tid + 256 * i;
    int d = c >> 3, p = c & 7;
    *(ushort8*)&vT[((size_t)bh * 128 + d) * 2048 + s0 + p * 8] = *(const ushort8*)&t[d * 80 + p * 8];
  }
}

// ---------------- retention: 128q blocks, 32q/wave, XCD-local, DMA dbuf K/V
#define LPAD 72
__global__ __launch_bounds__(256, 2) void retention_kernel(
    const unsigned short* __restrict__ qr, const unsigned short* __restrict__ kr,
    const unsigned short* __restrict__ vT, const unsigned short* __restrict__ Yg,
    unsigned short* __restrict__ Z)
{
  // shorts: kA[4096] kB[4096] vA[8192] vB[8192] lp[4*32*LPAD]
  __shared__ __attribute__((aligned(16))) unsigned short lds[24576 + 4 * 32 * LPAD];
  unsigned short* const lk0 = lds;
  unsigned short* const lk1 = lds + 4096;
  unsigned short* const lv0 = lds + 8192;
  unsigned short* const lv1 = lds + 16384;
  unsigned short* const lp  = lds + 24576;

  // XCD-locality: all 16 q-tiles of a bh on one XCD; heavy tiles first
  int lin = blockIdx.x;                     // 0..511
  int xcd = lin & 7, slot = lin >> 3;       // 64 slots/XCD
  int bh = xcd + 8 * (slot >> 4);
  int Q = 15 - (slot & 15);                 // q-tile index, heavy first
  int b = bh >> 4, h = bh & 15;
  float decay = __logf(1.f - exp2f(-5.f - (float)h));
  int tid = threadIdx.x, wave = tid >> 6, lane = tid & 63;
  int lr = lane & 15, lg = lane >> 4;
  const unsigned short* qbase = &qr[(size_t)bh * 2048 * 64];
  const unsigned short* kbase = &kr[(size_t)bh * 2048 * 64];
  const unsigned short* vbase = &vT[(size_t)bh * 128 * 2048];
  unsigned short* lpw = &lp[wave * 32 * LPAD];
  int swz = (lr & 7) << 3;                  // read-side XOR (shorts)

  float cf[4][4];
#pragma unroll
  for (int nb = 0; nb < 4; nb++)
#pragma unroll
    for (int r = 0; r < 4; r++)
      cf[nb][r] = __expf(-decay * (float)(nb * 16 + lg * 4 + r));

  auto stage = [&](int bufi, int t0) {
    const char* kg = (const char*)(kbase + (size_t)t0 * 64);   // contiguous 8KB
    const char* vg = (const char*)vbase + (size_t)t0 * 2;
    char* lk = (char*)(bufi ? lk1 : lk0);
    char* lv = (char*)(bufi ? lv1 : lv0);
#pragma unroll
    for (int i = 0; i < 2; i++) {
      int c = tid + i * 256;                 // 512 chunks of 16B (64 t-rows x 8)
      int r = c >> 3, j = c & 7;
      gload16(kg + r * 128 + ((j ^ (r & 7)) << 4), lk + c * 16);
    }
#pragma unroll
    for (int i = 0; i < 4; i++) {
      int c = tid + i * 256;                 // 1024 chunks of 16B (128 d-rows x 8)
      int d = c >> 3, j = c & 7;
      gload16(vg + (size_t)d * 4096 + ((j ^ (d & 7)) << 4), lv + c * 16);
    }
  };

  int s0 = Q * 128;
  int sq0 = s0 + wave * 16 + lr;             // g=0 q-row
  int sq1 = sq0 + 64;                        // g=1 q-row
  bf16x8 qf[2][2];
  qf[0][0] = *(const bf16x8*)&qbase[(size_t)sq0 * 64 + lg * 8];
  qf[0][1] = *(const bf16x8*)&qbase[(size_t)sq0 * 64 + 32 + lg * 8];
  qf[1][0] = *(const bf16x8*)&qbase[(size_t)sq1 * 64 + lg * 8];
  qf[1][1] = *(const bf16x8*)&qbase[(size_t)sq1 * 64 + 32 + lg * 8];
  f32x4 accv[2][8] = {};
  float rs[2] = {0.f, 0.f};
  int nt = 2 * Q + 2;

  stage(0, 0);
  for (int it = 0; it < nt; it++) {
    __syncthreads();                         // stage(it) done; buf^1 free
    if (it + 1 < nt) stage((it + 1) & 1, (it + 1) * 64);
    const unsigned short* lk = (it & 1) ? lk1 : lk0;
    const unsigned short* lv = (it & 1) ? lv1 : lv0;
    int t0 = it * 64;
    bool bnd = (it >= nt - 2);
    float rowf[2];
    rowf[0] = __expf(decay * (float)(sq0 - t0));
    rowf[1] = __expf(decay * (float)(sq1 - t0));
#pragma unroll
    for (int nb = 0; nb < 4; nb++) {
      bf16x8 a0 = *(const bf16x8*)&lk[((nb * 16 + lr) * 64 + lg * 8) ^ swz];
      bf16x8 a1 = *(const bf16x8*)&lk[((nb * 16 + lr) * 64 + 32 + lg * 8) ^ swz];
#pragma unroll
      for (int g = 0; g < 2; g++) {
        f32x4 sa = {};
        sa = mfma16(a0, qf[g][0], sa);       // S^T[t][q]
        sa = mfma16(a1, qf[g][1], sa);
        int sqg = g ? sq1 : sq0;
        float pv[4];
#pragma unroll
        for (int r = 0; r < 4; r++) {
          float w = rowf[g] * cf[nb][r];
          if (bnd) {
            int tt = t0 + nb * 16 + lg * 4 + r;
            w = (tt <= sqg) ? w : 0.f;
          }
          pv[r] = sa[r] * w;
          rs[g] += pv[r];
        }
        unsigned w0 = (unsigned)f2bf(pv[0]) | ((unsigned)f2bf(pv[1]) << 16);
        unsigned w1 = (unsigned)f2bf(pv[2]) | ((unsigned)f2bf(pv[3]) << 16);
        uint2 wv; wv.x = w0; wv.y = w1;
        *(uint2*)&lpw[(g * 16 + lr) * LPAD + nb * 16 + lg * 4] = wv;   // P[q][t]
      }
    }
#pragma unroll
    for (int kk = 0; kk < 2; kk++) {
      bf16x8 pa0 = *(const bf16x8*)&lpw[lr * LPAD + kk * 32 + lg * 8];
      bf16x8 pa1 = *(const bf16x8*)&lpw[(16 + lr) * LPAD + kk * 32 + lg * 8];
#pragma unroll
      for (int nb = 0; nb < 8; nb++) {
        bf16x8 bv = *(const bf16x8*)&lv[((nb * 16 + lr) * 64 + kk * 32 + lg * 8) ^ swz];
        accv[0][nb] = mfma16(pa0, bv, accv[0][nb]);
        accv[1][nb] = mfma16(pa1, bv, accv[1][nb]);
      }
    }
  }

  // epilogue per q-group: rowsum, geo-norm, denom, LN, silu gate
#pragma unroll
  for (int g = 0; g < 2; g++) {
    float rsg = rs[g];
    rsg += __shfl_xor(rsg, 16);
    rsg += __shfl_xor(rsg, 32);
    int srb = s0 + g * 64 + wave * 16 + lg * 4;
    const unsigned short* gb2 = &Yg[((size_t)(b * 2048 + srb)) * 6144 + 4096 + h * 128];
    unsigned short* zb = &Z[((size_t)(b * 2048 + srb)) * 2048 + h * 128];
#pragma unroll
    for (int r = 0; r < 4; r++) {
      float rsq = __shfl(rsg, lg * 4 + r);
      float sidx = (float)(srb + r);
      float geo = (1.f - __expf(decay * (sidx + 1.f))) * exp2f(5.f + (float)h);
      float invs = rsqrtf(geo);
      float den = fmaxf(fabsf(rsq * invs), 1.f);
      float scl = invs / den;
      float sm = 0.f, sq2 = 0.f;
#pragma unroll
      for (int nb = 0; nb < 8; nb++) {
        float v = accv[g][nb][r] * scl;
        sm += v; sq2 += v * v;
      }
      sm += __shfl_xor(sm, 1); sm += __shfl_xor(sm, 2);
      sm += __shfl_xor(sm, 4); sm += __shfl_xor(sm, 8);
      sq2 += __shfl_xor(sq2, 1); sq2 += __shfl_xor(sq2, 2);
      sq2 += __shfl_xor(sq2, 4); sq2 += __shfl_xor(sq2, 8);
      float mu = sm * (1.f / 128.f);
      float var = sq2 * (1.f / 128.f) - mu * mu;
      float istd = rsqrtf(var + 1e-5f);
#pragma unroll
      for (int nb = 0; nb < 8; nb++) {
        float v = accv[g][nb][r] * scl;
        float nrm = (v - mu) * istd;
        float gg = bf2f(gb2[(size_t)r * 6144 + nb * 16 + lr]);
        float sg = gg / (1.f + __expf(-gg));
        zb[(size_t)r * 2048 + nb * 16 + lr] = f2bf(nrm * sg);
      }
    }
  }
}

extern "C" void kernel_launch(void* const* d_in, const int* in_sizes, int n_in,
                              void* d_out, int out_size, void* d_ws, size_t ws_size,
                              hipStream_t stream) {
  const float* x  = (const float*)d_in[0];
  const float* Wq = (const float*)d_in[1];
  const float* bq = (const float*)d_in[2];
  const float* Wk = (const float*)d_in[3];
  const float* bk = (const float*)d_in[4];
  const float* Wv = (const float*)d_in[5];
  const float* bv = (const float*)d_in[6];
  const float* Wg = (const float*)d_in[7];
  const float* bg = (const float*)d_in[8];
  const float* Wo = (const float*)d_in[9];
  const float* bo = (const float*)d_in[10];

  char* ws = (char*)d_ws;
  unsigned short* xbf   = (unsigned short*)(ws);                 // [4096][1024]    8.4 MB
  unsigned short* wcatT = (unsigned short*)(ws + 8388608);       // [6144][1024]   12.6 MB
  unsigned short* woT   = (unsigned short*)(ws + 20971520);      // [1024][2048]    4.2 MB
  unsigned short* Y     = (unsigned short*)(ws + 25165824);      // [4096][6144]   50.3 MB
  unsigned short* qrb   = (unsigned short*)(ws + 75497472);      // [32][2048][64]  8.4 MB
  unsigned short* krb   = (unsigned short*)(ws + 83886080);      // [32][2048][64]  8.4 MB
  unsigned short* vT    = (unsigned short*)(ws + 92274688);      // [32][128][2048] 16.8 MB
  float*          bcat  = (float*)(ws + 109051904);              // [6144]
  unsigned short* Z     = xbf;   // aliases xbf+wcatT (16.8 MB), both dead after GEMM1

  // weights -> transposed bf16
  transpose_cast<<<dim3(16, 16), 256, 0, stream>>>(Wq, wcatT, 1024, 1024, 1024, 0);
  transpose_cast<<<dim3(16, 16), 256, 0, stream>>>(Wk, wcatT, 1024, 1024, 1024, 1024);
  transpose_cast<<<dim3(32, 16), 256, 0, stream>>>(Wv, wcatT, 1024, 2048, 1024, 2048);
  transpose_cast<<<dim3(32, 16), 256, 0, stream>>>(Wg, wcatT, 1024, 2048, 1024, 4096);
  transpose_cast<<<dim3(16, 32), 256, 0, stream>>>(Wo, woT, 2048, 1024, 2048, 0);
  biascat_kernel<<<24, 256, 0, stream>>>(bq, bk, bv, bg, bcat);
  cast_x_kernel<<<4096, 256, 0, stream>>>(x, xbf);

  // fused QKVG projection: Y = x @ [Wq|Wk|Wv|Wg] + bias (bf16 out)
  gemm_kernel<1, 128><<<dim3(48, 32), 256, 0, stream>>>(xbf, wcatT, bcat, Y, 4096, 6144, 1024);

  // prep: RoPE(q,k), v-transpose
  prep_qk_kernel<<<8192, 256, 0, stream>>>(Y, qrb, krb);
  prep_v_kernel<<<dim3(32, 32), 256, 0, stream>>>(Y, vT);

  // retention + LN + silu gate -> Z (bf16); g read directly from Y
  retention_kernel<<<512, 256, 0, stream>>>(qrb, krb, vT, Y, Z);

  // output projection: out = Z @ Wo + bo (fp32 out)
  gemm_kernel<0, 64><<<dim3(16, 32), 256, 0, stream>>>(Z, woT, bo, d_out, 4096, 1024, 2048);
}

// Round 5
// 210.846 us; speedup vs baseline: 1.1128x; 1.1128x over previous
//
#include <hip/hip_runtime.h>
#include <hip/hip_bf16.h>

typedef __attribute__((ext_vector_type(8))) unsigned short ushort8;
typedef __attribute__((ext_vector_type(4))) float f32x4;
typedef __attribute__((ext_vector_type(8))) __bf16 bf16x8;
typedef unsigned int u32_g __attribute__((address_space(1)));
typedef unsigned int u32_l __attribute__((address_space(3)));

__device__ __forceinline__ float bf2f(unsigned short u) {
  union { unsigned u; float f; } v; v.u = ((unsigned)u) << 16; return v.f;
}
__device__ __forceinline__ unsigned short f2bf(float f) {
  union { float f; unsigned u; } v; v.f = f;
  unsigned r = v.u + 0x7FFFu + ((v.u >> 16) & 1u);
  return (unsigned short)(r >> 16);
}
__device__ __forceinline__ f32x4 mfma16(bf16x8 a, bf16x8 b, f32x4 c) {
  return __builtin_amdgcn_mfma_f32_16x16x32_bf16(a, b, c, 0, 0, 0);
}
__device__ __forceinline__ void gload16(const void* g, void* l) {
  __builtin_amdgcn_global_load_lds((const u32_g*)g, (u32_l*)l, 16, 0, 0);
}

// ---------------- weight transpose+cast: W[K][N] fp32 -> WT[row_off+n][k] bf16
__global__ __launch_bounds__(256) void transpose_cast(
    const float* __restrict__ W, unsigned short* __restrict__ WT,
    int K, int N, int ldwt, int row_off)
{
  __shared__ unsigned short t[64 * 80];
  int n0 = blockIdx.x * 64, k0 = blockIdx.y * 64;
  int tid = threadIdx.x;
#pragma unroll
  for (int i = 0; i < 4; i++) {
    int c = tid + 256 * i;
    int r = c >> 4, q = c & 15;
    float4 v = *(const float4*)&W[(size_t)(k0 + r) * N + n0 + q * 4];
    t[(q * 4 + 0) * 80 + r] = f2bf(v.x);
    t[(q * 4 + 1) * 80 + r] = f2bf(v.y);
    t[(q * 4 + 2) * 80 + r] = f2bf(v.z);
    t[(q * 4 + 3) * 80 + r] = f2bf(v.w);
  }
  __syncthreads();
#pragma unroll
  for (int i = 0; i < 2; i++) {
    int c = tid + 256 * i;
    int n = c >> 3, p = c & 7;
    *(ushort8*)&WT[(size_t)(row_off + n0 + n) * ldwt + k0 + p * 8] =
        *(const ushort8*)&t[n * 80 + p * 8];
  }
}

__global__ void biascat_kernel(const float* __restrict__ bq, const float* __restrict__ bk,
                               const float* __restrict__ bv, const float* __restrict__ bg,
                               float* __restrict__ bcat)
{
  int i = blockIdx.x * 256 + threadIdx.x;   // 6144
  float v;
  if (i < 1024) v = bq[i];
  else if (i < 2048) v = bk[i - 1024];
  else if (i < 4096) v = bv[i - 2048];
  else v = bg[i - 4096];
  bcat[i] = v;
}

__global__ void cast_x_kernel(const float* __restrict__ x, unsigned short* __restrict__ xb)
{
  size_t i = (size_t)(blockIdx.x * 256 + threadIdx.x) * 4;
  float4 v = *(const float4*)&x[i];
  unsigned r0 = (unsigned)f2bf(v.x) | ((unsigned)f2bf(v.y) << 16);
  unsigned r1 = (unsigned)f2bf(v.z) | ((unsigned)f2bf(v.w) << 16);
  uint2 o; o.x = r0; o.y = r1;
  *(uint2*)&xb[i] = o;
}

// ---------------- GEMM: dbuf + single barrier + both-sides swizzle
template<int OUT_BF16, int BN>
__global__ __launch_bounds__(256, 2) void gemm_kernel(
    const unsigned short* __restrict__ A, const unsigned short* __restrict__ BT,
    const float* __restrict__ bias, void* __restrict__ Cout,
    int M, int N, int K)
{
  __shared__ unsigned short As[2 * 128 * 64];
  __shared__ unsigned short Bs[2 * BN * 64];
  constexpr int NR = BN / 32;
  int tid = threadIdx.x;
  int wave = tid >> 6, lane = tid & 63;
  int lr = lane & 15, lg = lane >> 4;
  // bijective XCD swizzle (nwg % 8 == 0 for all our grids)
  int gx = gridDim.x;
  int lin = blockIdx.x + gx * blockIdx.y;
  int cpx = (gx * gridDim.y) >> 3;
  int lin2 = (lin & 7) * cpx + (lin >> 3);
  int m0 = (lin2 / gx) * 128, n0 = (lin2 % gx) * BN;
  int wr = (wave >> 1) * 64, wc = (wave & 1) * (BN / 2);
  int srow = tid >> 3, sc8 = tid & 7;
  int ssw = (sc8 ^ (srow & 7)) * 8;          // swizzled source chunk (shorts)
  const unsigned short* ga = &A[(size_t)(m0 + srow) * K + ssw];
  const unsigned short* gb = &BT[(size_t)(n0 + srow) * K + ssw];
  int rsw = lr & 7;                          // read-side chunk XOR
  f32x4 acc[4][NR] = {};

  auto stage = [&](int buf, int k0) {
    char* la = (char*)&As[buf * 128 * 64];
    char* lb = (char*)&Bs[buf * BN * 64];
#pragma unroll
    for (int i = 0; i < 4; i++)
      gload16(ga + (size_t)i * 32 * K + k0, la + (tid + i * 256) * 16);
#pragma unroll
    for (int i = 0; i < NR; i++)
      gload16(gb + (size_t)i * 32 * K + k0, lb + (tid + i * 256) * 16);
  };

  int nk = K >> 6;
  stage(0, 0);
  for (int it = 0; it < nk; it++) {
    __syncthreads();                          // drains stage(it); all waves done reading buf^1
    if (it + 1 < nk) stage((it + 1) & 1, (it + 1) * 64);
    const unsigned short* as = &As[(it & 1) * 128 * 64];
    const unsigned short* bs = &Bs[(it & 1) * BN * 64];
#pragma unroll
    for (int kk = 0; kk < 2; kk++) {
      int csw = ((kk * 4 + lg) ^ rsw) * 8;
      bf16x8 af[4], bfr[NR];
#pragma unroll
      for (int m = 0; m < 4; m++)
        af[m] = *(const bf16x8*)&as[(wr + m * 16 + lr) * 64 + csw];
#pragma unroll
      for (int n = 0; n < NR; n++)
        bfr[n] = *(const bf16x8*)&bs[(wc + n * 16 + lr) * 64 + csw];
#pragma unroll
      for (int m = 0; m < 4; m++)
#pragma unroll
        for (int n = 0; n < NR; n++)
          acc[m][n] = mfma16(af[m], bfr[n], acc[m][n]);
    }
  }
#pragma unroll
  for (int m = 0; m < 4; m++) {
#pragma unroll
    for (int n = 0; n < NR; n++) {
      int col = n0 + wc + n * 16 + lr;
      float bv = bias ? bias[col] : 0.f;
#pragma unroll
      for (int r = 0; r < 4; r++) {
        int row = m0 + wr + m * 16 + lg * 4 + r;
        float v = acc[m][n][r] + bv;
        if (OUT_BF16)
          ((unsigned short*)Cout)[(size_t)row * N + col] = f2bf(v);
        else
          ((float*)Cout)[(size_t)row * N + col] = v;
      }
    }
  }
}

// ---------------- prep: RoPE for q,k -> [BH][S][64] bf16
__global__ __launch_bounds__(256) void prep_qk_kernel(
    const unsigned short* __restrict__ Y,
    unsigned short* __restrict__ qr, unsigned short* __restrict__ kr)
{
  int t = blockIdx.x * 256 + threadIdx.x;  // [bs:4096][h:16][j:32]
  int j = t & 31;
  int h = (t >> 5) & 15;
  int bs = t >> 9;
  int s = bs & 2047;
  int b = bs >> 11;
  float ang = __expf(-0.29710774f * (float)j);   // 10000^(-j/31)
  float th = (float)s * ang;
  float sn, cs;
  __sincosf(th, &sn, &cs);
  const unsigned short* yq = &Y[(size_t)bs * 6144 + h * 64 + 2 * j];
  unsigned qv = *(const unsigned*)yq;
  unsigned kv = *(const unsigned*)(yq + 1024);
  float q0 = bf2f((unsigned short)(qv & 0xffff));
  float q1 = bf2f((unsigned short)(qv >> 16));
  float k0 = bf2f((unsigned short)(kv & 0xffff)) * 0.125f;
  float k1 = bf2f((unsigned short)(kv >> 16)) * 0.125f;
  float qr0 = q0 * cs - q1 * sn, qr1 = q1 * cs + q0 * sn;
  float kr0 = k0 * cs - k1 * sn, kr1 = k1 * cs + k0 * sn;
  size_t o = ((size_t)(b * 16 + h) * 2048 + s) * 64 + 2 * j;
  *(unsigned*)&qr[o] = (unsigned)f2bf(qr0) | ((unsigned)f2bf(qr1) << 16);
  *(unsigned*)&kr[o] = (unsigned)f2bf(kr0) | ((unsigned)f2bf(kr1) << 16);
}

// ---------------- prep: v transpose -> vT[BH][128][2048] bf16
__global__ __launch_bounds__(256) void prep_v_kernel(
    const unsigned short* __restrict__ Y, unsigned short* __restrict__ vT)
{
  __shared__ unsigned short t[128 * 80];
  int s0 = blockIdx.x * 64;
  int bh = blockIdx.y;
  int b = bh >> 4, h = bh & 15;
  int tid = threadIdx.x;
#pragma unroll
  for (int i = 0; i < 4; i++) {
    int c = tid + 256 * i;
    int r = c >> 4, p = c & 15;
    ushort8 v = *(const ushort8*)&Y[(size_t)(b * 2048 + s0 + r) * 6144 + 2048 + h * 128 + p * 8];
#pragma unroll
    for (int e = 0; e < 8; e++) t[(p * 8 + e) * 80 + r] = v[e];
  }
  __syncthreads();
#pragma unroll
  for (int i = 0; i < 4; i++) {
    int c = tid + 256 * i;
    int d = c >> 3, p = c & 7;
    *(ushort8*)&vT[((size_t)bh * 128 + d) * 2048 + s0 + p * 8] = *(const ushort8*)&t[d * 80 + p * 8];
  }
}

// ---------------- retention: swapped-QK, XCD-local bh, DMA double-buffered K/V
// (R3 balanced-pair structure: every block does exactly 33 tile-iters)
#define LPAD 72
__global__ __launch_bounds__(256, 2) void retention_kernel(
    const unsigned short* __restrict__ qr, const unsigned short* __restrict__ kr,
    const unsigned short* __restrict__ vT, const unsigned short* __restrict__ Yg,
    unsigned short* __restrict__ Z)
{
  // shorts: kA[4096] kB[4096] vA[8192] vB[8192] lp[4*16*72]
  __shared__ __attribute__((aligned(16))) unsigned short lds[24576 + 4 * 16 * LPAD];
  unsigned short* const lk0 = lds;
  unsigned short* const lk1 = lds + 4096;
  unsigned short* const lv0 = lds + 8192;
  unsigned short* const lv1 = lds + 16384;
  unsigned short* const lp  = lds + 24576;

  // XCD-locality mapping: all 16 blocks of a bh on one XCD (wgid%8 round-robin)
  int lin = blockIdx.x;            // 0..511
  int xcd = lin & 7, slot = lin >> 3;       // slot 0..63
  int bh = xcd + 8 * (slot >> 4);           // 4 bh per XCD
  int bx = slot & 15;                       // pair index
  int b = bh >> 4, h = bh & 15;
  float decay = __logf(1.f - exp2f(-5.f - (float)h));
  int tid = threadIdx.x, wave = tid >> 6, lane = tid & 63;
  int lr = lane & 15, lg = lane >> 4;
  const unsigned short* qbase = &qr[(size_t)bh * 2048 * 64];
  const unsigned short* kbase = &kr[(size_t)bh * 2048 * 64];
  const unsigned short* vbase = &vT[(size_t)bh * 128 * 2048];
  unsigned short* lpw = &lp[wave * 16 * LPAD];
  int swz = (lr & 7) << 3;                  // read-side XOR swizzle (shorts)

  float cf[4][4];
#pragma unroll
  for (int nb = 0; nb < 4; nb++)
#pragma unroll
    for (int r = 0; r < 4; r++)
      cf[nb][r] = __expf(-decay * (float)(nb * 16 + lg * 4 + r));

  auto stage = [&](int bufi, int t0) {
    const char* kg = (const char*)(kbase + (size_t)t0 * 64);   // contiguous 8KB
    const char* vg = (const char*)vbase + (size_t)t0 * 2;
    char* lk = (char*)(bufi ? lk1 : lk0);
    char* lv = (char*)(bufi ? lv1 : lv0);
#pragma unroll
    for (int i = 0; i < 2; i++) {
      int c = tid + i * 256;                 // 512 chunks of 16B
      int r = c >> 3, j = c & 7;
      gload16(kg + r * 128 + ((j ^ (r & 7)) << 4), lk + c * 16);
    }
#pragma unroll
    for (int i = 0; i < 4; i++) {
      int c = tid + i * 256;                 // 1024 chunks of 16B
      int d = c >> 3, j = c & 7;
      gload16(vg + (size_t)d * 4096 + ((j ^ (d & 7)) << 4), lv + c * 16);
    }
  };

  for (int pass = 0; pass < 2; pass++) {
    int stile = pass ? 31 - bx : bx;
    int s0 = stile * 64;
    int sq = s0 + wave * 16 + lr;            // this lane's q-row
    bf16x8 qf0 = *(const bf16x8*)&qbase[(size_t)sq * 64 + lg * 8];
    bf16x8 qf1 = *(const bf16x8*)&qbase[(size_t)sq * 64 + 32 + lg * 8];
    f32x4 accv[8] = {};
    float rs = 0.f;
    int nt = stile + 1;

    stage(0, 0);
    __syncthreads();
    for (int it = 0; it < nt; it++) {
      int t0 = it * 64;
      if (it + 1 < nt) stage((it + 1) & 1, t0 + 64);   // overlap with compute
      const unsigned short* lk = (it & 1) ? lk1 : lk0;
      const unsigned short* lv = (it & 1) ? lv1 : lv0;
      bool bnd = (it == nt - 1);
      float rowf = __expf(decay * (float)(sq - t0));
#pragma unroll
      for (int nb = 0; nb < 4; nb++) {
        f32x4 sa = {};
        bf16x8 a0 = *(const bf16x8*)&lk[((nb * 16 + lr) * 64 + lg * 8) ^ swz];
        bf16x8 a1 = *(const bf16x8*)&lk[((nb * 16 + lr) * 64 + 32 + lg * 8) ^ swz];
        sa = mfma16(a0, qf0, sa);            // S^T[t][q]
        sa = mfma16(a1, qf1, sa);
        float pv[4];
#pragma unroll
        for (int r = 0; r < 4; r++) {
          float w = rowf * cf[nb][r];
          if (bnd) {
            int tt = t0 + nb * 16 + lg * 4 + r;
            w = (tt <= sq) ? w : 0.f;
          }
          pv[r] = sa[r] * w;
          rs += pv[r];
        }
        unsigned w0 = (unsigned)f2bf(pv[0]) | ((unsigned)f2bf(pv[1]) << 16);
        unsigned w1 = (unsigned)f2bf(pv[2]) | ((unsigned)f2bf(pv[3]) << 16);
        uint2 wv; wv.x = w0; wv.y = w1;
        *(uint2*)&lpw[lr * LPAD + nb * 16 + lg * 4] = wv;   // P[q][t]
      }
#pragma unroll
      for (int kk = 0; kk < 2; kk++) {
        bf16x8 pa = *(const bf16x8*)&lpw[lr * LPAD + kk * 32 + lg * 8];
#pragma unroll
        for (int nb = 0; nb < 8; nb++) {
          bf16x8 bv = *(const bf16x8*)&lv[((nb * 16 + lr) * 64 + kk * 32 + lg * 8) ^ swz];
          accv[nb] = mfma16(pa, bv, accv[nb]);
        }
      }
      __syncthreads();                       // drains next-tile DMA + frees bufs
    }

    // epilogue: rowsum reduce over lg groups (q-row = lr within wave)
    rs += __shfl_xor(rs, 16);
    rs += __shfl_xor(rs, 32);
    int srb = s0 + wave * 16 + lg * 4;
    const unsigned short* gb2 = &Yg[((size_t)(b * 2048 + srb)) * 6144 + 4096 + h * 128];
    unsigned short* zb = &Z[((size_t)(b * 2048 + srb)) * 2048 + h * 128];
#pragma unroll
    for (int r = 0; r < 4; r++) {
      float rsq = __shfl(rs, lg * 4 + r);
      float sidx = (float)(srb + r);
      float geo = (1.f - __expf(decay * (sidx + 1.f))) * exp2f(5.f + (float)h);
      float invs = rsqrtf(geo);
      float den = fmaxf(fabsf(rsq * invs), 1.f);
      float scl = invs / den;
      float sm = 0.f, sq2 = 0.f;
#pragma unroll
      for (int nb = 0; nb < 8; nb++) {
        float v = accv[nb][r] * scl;
        sm += v; sq2 += v * v;
      }
      sm += __shfl_xor(sm, 1); sm += __shfl_xor(sm, 2);
      sm += __shfl_xor(sm, 4); sm += __shfl_xor(sm, 8);
      sq2 += __shfl_xor(sq2, 1); sq2 += __shfl_xor(sq2, 2);
      sq2 += __shfl_xor(sq2, 4); sq2 += __shfl_xor(sq2, 8);
      float mu = sm * (1.f / 128.f);
      float var = sq2 * (1.f / 128.f) - mu * mu;
      float istd = rsqrtf(var + 1e-5f);
#pragma unroll
      for (int nb = 0; nb < 8; nb++) {
        float v = accv[nb][r] * scl;
        float nrm = (v - mu) * istd;
        float g = bf2f(gb2[(size_t)r * 6144 + nb * 16 + lr]);
        float sg = g / (1.f + __expf(-g));
        zb[(size_t)r * 2048 + nb * 16 + lr] = f2bf(nrm * sg);
      }
    }
  }
}

extern "C" void kernel_launch(void* const* d_in, const int* in_sizes, int n_in,
                              void* d_out, int out_size, void* d_ws, size_t ws_size,
                              hipStream_t stream) {
  const float* x  = (const float*)d_in[0];
  const float* Wq = (const float*)d_in[1];
  const float* bq = (const float*)d_in[2];
  const float* Wk = (const float*)d_in[3];
  const float* bk = (const float*)d_in[4];
  const float* Wv = (const float*)d_in[5];
  const float* bv = (const float*)d_in[6];
  const float* Wg = (const float*)d_in[7];
  const float* bg = (const float*)d_in[8];
  const float* Wo = (const float*)d_in[9];
  const float* bo = (const float*)d_in[10];

  char* ws = (char*)d_ws;
  unsigned short* xbf   = (unsigned short*)(ws);                 // [4096][1024]    8.4 MB
  unsigned short* wcatT = (unsigned short*)(ws + 8388608);       // [6144][1024]   12.6 MB
  unsigned short* woT   = (unsigned short*)(ws + 20971520);      // [1024][2048]    4.2 MB
  unsigned short* Y     = (unsigned short*)(ws + 25165824);      // [4096][6144]   50.3 MB
  unsigned short* qrb   = (unsigned short*)(ws + 75497472);      // [32][2048][64]  8.4 MB
  unsigned short* krb   = (unsigned short*)(ws + 83886080);      // [32][2048][64]  8.4 MB
  unsigned short* vT    = (unsigned short*)(ws + 92274688);      // [32][128][2048] 16.8 MB
  float*          bcat  = (float*)(ws + 109051904);              // [6144]
  unsigned short* Z     = xbf;   // aliases xbf+wcatT (16.8 MB), both dead after GEMM1

  // weights -> transposed bf16
  transpose_cast<<<dim3(16, 16), 256, 0, stream>>>(Wq, wcatT, 1024, 1024, 1024, 0);
  transpose_cast<<<dim3(16, 16), 256, 0, stream>>>(Wk, wcatT, 1024, 1024, 1024, 1024);
  transpose_cast<<<dim3(32, 16), 256, 0, stream>>>(Wv, wcatT, 1024, 2048, 1024, 2048);
  transpose_cast<<<dim3(32, 16), 256, 0, stream>>>(Wg, wcatT, 1024, 2048, 1024, 4096);
  transpose_cast<<<dim3(16, 32), 256, 0, stream>>>(Wo, woT, 2048, 1024, 2048, 0);
  biascat_kernel<<<24, 256, 0, stream>>>(bq, bk, bv, bg, bcat);
  cast_x_kernel<<<4096, 256, 0, stream>>>(x, xbf);

  // fused QKVG projection: Y = x @ [Wq|Wk|Wv|Wg] + bias (bf16 out)
  gemm_kernel<1, 128><<<dim3(48, 32), 256, 0, stream>>>(xbf, wcatT, bcat, Y, 4096, 6144, 1024);

  // prep: RoPE(q,k), v-transpose
  prep_qk_kernel<<<8192, 256, 0, stream>>>(Y, qrb, krb);
  prep_v_kernel<<<dim3(32, 32), 256, 0, stream>>>(Y, vT);

  // retention + LN + silu gate -> Z (bf16); g read directly from Y
  retention_kernel<<<512, 256, 0, stream>>>(qrb, krb, vT, Y, Z);

  // output projection: out = Z @ Wo + bo (fp32 out)
  gemm_kernel<0, 64><<<dim3(16, 32), 256, 0, stream>>>(Z, woT, bo, d_out, 4096, 1024, 2048);
}

// Round 6
// 207.638 us; speedup vs baseline: 1.1300x; 1.0155x over previous
//
#include <hip/hip_runtime.h>
#include <hip/hip_bf16.h>

typedef __attribute__((ext_vector_type(8))) unsigned short ushort8;
typedef __attribute__((ext_vector_type(4))) float f32x4;
typedef __attribute__((ext_vector_type(8))) __bf16 bf16x8;
typedef unsigned int u32_g __attribute__((address_space(1)));
typedef unsigned int u32_l __attribute__((address_space(3)));

__device__ __forceinline__ float bf2f(unsigned short u) {
  union { unsigned u; float f; } v; v.u = ((unsigned)u) << 16; return v.f;
}
__device__ __forceinline__ unsigned short f2bf(float f) {
  union { float f; unsigned u; } v; v.f = f;
  unsigned r = v.u + 0x7FFFu + ((v.u >> 16) & 1u);
  return (unsigned short)(r >> 16);
}
__device__ __forceinline__ f32x4 mfma16(bf16x8 a, bf16x8 b, f32x4 c) {
  return __builtin_amdgcn_mfma_f32_16x16x32_bf16(a, b, c, 0, 0, 0);
}
__device__ __forceinline__ void gload16(const void* g, void* l) {
  __builtin_amdgcn_global_load_lds((const u32_g*)g, (u32_l*)l, 16, 0, 0);
}

// ---------------- weight transpose+cast: W[K][N] fp32 -> WT[row_off+n][k] bf16
__global__ __launch_bounds__(256) void transpose_cast(
    const float* __restrict__ W, unsigned short* __restrict__ WT,
    int K, int N, int ldwt, int row_off)
{
  __shared__ unsigned short t[64 * 80];
  int n0 = blockIdx.x * 64, k0 = blockIdx.y * 64;
  int tid = threadIdx.x;
#pragma unroll
  for (int i = 0; i < 4; i++) {
    int c = tid + 256 * i;
    int r = c >> 4, q = c & 15;
    float4 v = *(const float4*)&W[(size_t)(k0 + r) * N + n0 + q * 4];
    t[(q * 4 + 0) * 80 + r] = f2bf(v.x);
    t[(q * 4 + 1) * 80 + r] = f2bf(v.y);
    t[(q * 4 + 2) * 80 + r] = f2bf(v.z);
    t[(q * 4 + 3) * 80 + r] = f2bf(v.w);
  }
  __syncthreads();
#pragma unroll
  for (int i = 0; i < 2; i++) {
    int c = tid + 256 * i;
    int n = c >> 3, p = c & 7;
    *(ushort8*)&WT[(size_t)(row_off + n0 + n) * ldwt + k0 + p * 8] =
        *(const ushort8*)&t[n * 80 + p * 8];
  }
}

__global__ void biascat_kernel(const float* __restrict__ bq, const float* __restrict__ bk,
                               const float* __restrict__ bv, const float* __restrict__ bg,
                               float* __restrict__ bcat)
{
  int i = blockIdx.x * 256 + threadIdx.x;   // 6144
  float v;
  if (i < 1024) v = bq[i];
  else if (i < 2048) v = bk[i - 1024];
  else if (i < 4096) v = bv[i - 2048];
  else v = bg[i - 4096];
  bcat[i] = v;
}

__global__ void cast_x_kernel(const float* __restrict__ x, unsigned short* __restrict__ xb)
{
  size_t i = (size_t)(blockIdx.x * 256 + threadIdx.x) * 4;
  float4 v = *(const float4*)&x[i];
  unsigned r0 = (unsigned)f2bf(v.x) | ((unsigned)f2bf(v.y) << 16);
  unsigned r1 = (unsigned)f2bf(v.z) | ((unsigned)f2bf(v.w) << 16);
  uint2 o; o.x = r0; o.y = r1;
  *(uint2*)&xb[i] = o;
}

// ---------------- GEMM-256: 256x256 tile, 4-phase counted-vmcnt pipeline
// 512 thr (8 waves, wave-tile 256x32). LDS 128KB: 2 buf x (A[256][64]+B[256][64]).
// Stage order per next K-tile: B0,B1,A0,A1 (one half per phase, 2 gload16/thr).
// top: vmcnt(2) (B0,B1,A0 of cur landed, A1 may fly); mid: vmcnt(4) (A1 landed).
template<int OUT_BF16>
__global__ __launch_bounds__(512, 1) void gemm256_kernel(
    const unsigned short* __restrict__ A, const unsigned short* __restrict__ BT,
    const float* __restrict__ bias, void* __restrict__ Cout,
    int M, int N, int K)
{
  __shared__ __attribute__((aligned(16))) unsigned short lds[65536]; // 128 KiB
  int tid = threadIdx.x, wave = tid >> 6, lane = tid & 63;
  int lr = lane & 15, lg = lane >> 4;
  int gx = gridDim.x;
  int lin = blockIdx.x + gx * blockIdx.y;
  int cpx = (gx * gridDim.y) >> 3;              // nwg % 8 == 0
  int lin2 = (lin & 7) * cpx + (lin >> 3);
  int m0 = (lin2 / gx) * 256, n0 = (lin2 % gx) * 256;
  int wc = wave * 32;
  // staging: thread covers chunks tid and tid+512 of each 1024-chunk half
  int r0 = tid >> 3, j0 = tid & 7;
  int sw0 = (j0 ^ (r0 & 7)) << 3;               // pre-swizzled col (shorts)
  int sw1 = (j0 ^ ((r0 + 64) & 7)) << 3;

  auto stageh = [&](int buf, int h, int kt) {
    const unsigned short* src;
    int halfrow, dsts;                          // dst base in shorts
    if (h >= 2) { src = A  + (size_t)m0 * K; halfrow = (h - 2) * 128;
                  dsts = buf * 32768 + (h - 2) * 8192; }
    else        { src = BT + (size_t)n0 * K; halfrow = h * 128;
                  dsts = buf * 32768 + 16384 + h * 8192; }
    const unsigned short* s0 = src + (size_t)(halfrow + r0) * K + kt * 64 + sw0;
    const unsigned short* s1 = src + (size_t)(halfrow + r0 + 64) * K + kt * 64 + sw1;
    gload16(s0, (char*)lds + dsts * 2 + tid * 16);
    gload16(s1, (char*)lds + dsts * 2 + (tid + 512) * 16);
  };

  f32x4 acc[16][2] = {};
  int nk = K >> 6;
  // prologue: tile 0, order B0,B1,A0,A1
  stageh(0, 0, 0); stageh(0, 1, 0); stageh(0, 2, 0); stageh(0, 3, 0);

#define QPHASE(P) { \
  if (pf) stageh(nxt, (P), kt + 1); \
  __builtin_amdgcn_s_setprio(1); \
  _Pragma("unroll") \
  for (int kk = 0; kk < 2; kk++) { \
    bf16x8 af[4]; \
    _Pragma("unroll") \
    for (int i = 0; i < 4; i++) \
      af[i] = *(const bf16x8*)&as[((P) * 64 + i * 16 + lr) * 64 + (((kk * 4 + lg) ^ (lr & 7)) << 3)]; \
    _Pragma("unroll") \
    for (int i = 0; i < 4; i++) \
      _Pragma("unroll") \
      for (int n = 0; n < 2; n++) \
        acc[(P) * 4 + i][n] = mfma16(af[i], bfr[kk][n], acc[(P) * 4 + i][n]); \
  } \
  __builtin_amdgcn_s_setprio(0); \
}

  for (int kt = 0; kt < nk; kt++) {
    int cur = kt & 1, nxt = cur ^ 1;
    bool pf = (kt + 1 < nk);
    const unsigned short* as = lds + cur * 32768;
    const unsigned short* bs = as + 16384;
    __builtin_amdgcn_sched_barrier(0);
    asm volatile("s_waitcnt lgkmcnt(0) vmcnt(2)" ::: "memory");
    __builtin_amdgcn_sched_barrier(0);
    __builtin_amdgcn_s_barrier();
    __builtin_amdgcn_sched_barrier(0);
    // hoisted B fragments (both halves landed at top wait)
    bf16x8 bfr[2][2];
#pragma unroll
    for (int kk = 0; kk < 2; kk++)
#pragma unroll
      for (int n = 0; n < 2; n++)
        bfr[kk][n] = *(const bf16x8*)&bs[(wc + n * 16 + lr) * 64 + (((kk * 4 + lg) ^ (lr & 7)) << 3)];
    QPHASE(0)
    QPHASE(1)
    __builtin_amdgcn_sched_barrier(0);
    if (pf) asm volatile("s_waitcnt vmcnt(4)" ::: "memory");
    else    asm volatile("s_waitcnt vmcnt(0)" ::: "memory");
    __builtin_amdgcn_sched_barrier(0);
    __builtin_amdgcn_s_barrier();
    __builtin_amdgcn_sched_barrier(0);
    QPHASE(2)
    QPHASE(3)
  }
#undef QPHASE

#pragma unroll
  for (int mt = 0; mt < 16; mt++) {
#pragma unroll
    for (int n = 0; n < 2; n++) {
      int col = n0 + wc + n * 16 + lr;
      float bv = bias ? bias[col] : 0.f;
#pragma unroll
      for (int r = 0; r < 4; r++) {
        int row = m0 + mt * 16 + lg * 4 + r;
        float v = acc[mt][n][r] + bv;
        if (OUT_BF16)
          ((unsigned short*)Cout)[(size_t)row * N + col] = f2bf(v);
        else
          ((float*)Cout)[(size_t)row * N + col] = v;
      }
    }
  }
}

// ---------------- GEMM (128-tile, dbuf, swizzled) for the output projection
template<int OUT_BF16, int BN>
__global__ __launch_bounds__(256, 2) void gemm_kernel(
    const unsigned short* __restrict__ A, const unsigned short* __restrict__ BT,
    const float* __restrict__ bias, void* __restrict__ Cout,
    int M, int N, int K)
{
  __shared__ unsigned short As[2 * 128 * 64];
  __shared__ unsigned short Bs[2 * BN * 64];
  constexpr int NR = BN / 32;
  int tid = threadIdx.x;
  int wave = tid >> 6, lane = tid & 63;
  int lr = lane & 15, lg = lane >> 4;
  int gx = gridDim.x;
  int lin = blockIdx.x + gx * blockIdx.y;
  int cpx = (gx * gridDim.y) >> 3;
  int lin2 = (lin & 7) * cpx + (lin >> 3);
  int m0 = (lin2 / gx) * 128, n0 = (lin2 % gx) * BN;
  int wr = (wave >> 1) * 64, wc = (wave & 1) * (BN / 2);
  int srow = tid >> 3, sc8 = tid & 7;
  int ssw = (sc8 ^ (srow & 7)) * 8;
  const unsigned short* ga = &A[(size_t)(m0 + srow) * K + ssw];
  const unsigned short* gb = &BT[(size_t)(n0 + srow) * K + ssw];
  int rsw = lr & 7;
  f32x4 acc[4][NR] = {};

  auto stage = [&](int buf, int k0) {
    char* la = (char*)&As[buf * 128 * 64];
    char* lb = (char*)&Bs[buf * BN * 64];
#pragma unroll
    for (int i = 0; i < 4; i++)
      gload16(ga + (size_t)i * 32 * K + k0, la + (tid + i * 256) * 16);
#pragma unroll
    for (int i = 0; i < NR; i++)
      gload16(gb + (size_t)i * 32 * K + k0, lb + (tid + i * 256) * 16);
  };

  int nk = K >> 6;
  stage(0, 0);
  for (int it = 0; it < nk; it++) {
    __syncthreads();
    if (it + 1 < nk) stage((it + 1) & 1, (it + 1) * 64);
    const unsigned short* as = &As[(it & 1) * 128 * 64];
    const unsigned short* bs = &Bs[(it & 1) * BN * 64];
#pragma unroll
    for (int kk = 0; kk < 2; kk++) {
      int csw = ((kk * 4 + lg) ^ rsw) * 8;
      bf16x8 af[4], bfr[NR];
#pragma unroll
      for (int m = 0; m < 4; m++)
        af[m] = *(const bf16x8*)&as[(wr + m * 16 + lr) * 64 + csw];
#pragma unroll
      for (int n = 0; n < NR; n++)
        bfr[n] = *(const bf16x8*)&bs[(wc + n * 16 + lr) * 64 + csw];
#pragma unroll
      for (int m = 0; m < 4; m++)
#pragma unroll
        for (int n = 0; n < NR; n++)
          acc[m][n] = mfma16(af[m], bfr[n], acc[m][n]);
    }
  }
#pragma unroll
  for (int m = 0; m < 4; m++) {
#pragma unroll
    for (int n = 0; n < NR; n++) {
      int col = n0 + wc + n * 16 + lr;
      float bv = bias ? bias[col] : 0.f;
#pragma unroll
      for (int r = 0; r < 4; r++) {
        int row = m0 + wr + m * 16 + lg * 4 + r;
        float v = acc[m][n][r] + bv;
        if (OUT_BF16)
          ((unsigned short*)Cout)[(size_t)row * N + col] = f2bf(v);
        else
          ((float*)Cout)[(size_t)row * N + col] = v;
      }
    }
  }
}

// ---------------- prep: RoPE for q,k -> [BH][S][64] bf16
__global__ __launch_bounds__(256) void prep_qk_kernel(
    const unsigned short* __restrict__ Y,
    unsigned short* __restrict__ qr, unsigned short* __restrict__ kr)
{
  int t = blockIdx.x * 256 + threadIdx.x;  // [bs:4096][h:16][j:32]
  int j = t & 31;
  int h = (t >> 5) & 15;
  int bs = t >> 9;
  int s = bs & 2047;
  int b = bs >> 11;
  float ang = __expf(-0.29710774f * (float)j);   // 10000^(-j/31)
  float th = (float)s * ang;
  float sn, cs;
  __sincosf(th, &sn, &cs);
  const unsigned short* yq = &Y[(size_t)bs * 6144 + h * 64 + 2 * j];
  unsigned qv = *(const unsigned*)yq;
  unsigned kv = *(const unsigned*)(yq + 1024);
  float q0 = bf2f((unsigned short)(qv & 0xffff));
  float q1 = bf2f((unsigned short)(qv >> 16));
  float k0 = bf2f((unsigned short)(kv & 0xffff)) * 0.125f;
  float k1 = bf2f((unsigned short)(kv >> 16)) * 0.125f;
  float qr0 = q0 * cs - q1 * sn, qr1 = q1 * cs + q0 * sn;
  float kr0 = k0 * cs - k1 * sn, kr1 = k1 * cs + k0 * sn;
  size_t o = ((size_t)(b * 16 + h) * 2048 + s) * 64 + 2 * j;
  *(unsigned*)&qr[o] = (unsigned)f2bf(qr0) | ((unsigned)f2bf(qr1) << 16);
  *(unsigned*)&kr[o] = (unsigned)f2bf(kr0) | ((unsigned)f2bf(kr1) << 16);
}

// ---------------- prep: v transpose -> vT[BH][128][2048] bf16
__global__ __launch_bounds__(256) void prep_v_kernel(
    const unsigned short* __restrict__ Y, unsigned short* __restrict__ vT)
{
  __shared__ unsigned short t[128 * 80];
  int s0 = blockIdx.x * 64;
  int bh = blockIdx.y;
  int b = bh >> 4, h = bh & 15;
  int tid = threadIdx.x;
#pragma unroll
  for (int i = 0; i < 4; i++) {
    int c = tid + 256 * i;
    int r = c >> 4, p = c & 15;
    ushort8 v = *(const ushort8*)&Y[(size_t)(b * 2048 + s0 + r) * 6144 + 2048 + h * 128 + p * 8];
#pragma unroll
    for (int e = 0; e < 8; e++) t[(p * 8 + e) * 80 + r] = v[e];
  }
  __syncthreads();
#pragma unroll
  for (int i = 0; i < 4; i++) {
    int c = tid + 256 * i;
    int d = c >> 3, p = c & 7;
    *(ushort8*)&vT[((size_t)bh * 128 + d) * 2048 + s0 + p * 8] = *(const ushort8*)&t[d * 80 + p * 8];
  }
}

// ---------------- retention: swapped-QK, XCD-local bh, DMA double-buffered K/V
// (R3 balanced-pair structure: every block does exactly 33 tile-iters)
#define LPAD 72
__global__ __launch_bounds__(256, 2) void retention_kernel(
    const unsigned short* __restrict__ qr, const unsigned short* __restrict__ kr,
    const unsigned short* __restrict__ vT, const unsigned short* __restrict__ Yg,
    unsigned short* __restrict__ Z)
{
  // shorts: kA[4096] kB[4096] vA[8192] vB[8192] lp[4*16*72]
  __shared__ __attribute__((aligned(16))) unsigned short lds[24576 + 4 * 16 * LPAD];
  unsigned short* const lk0 = lds;
  unsigned short* const lk1 = lds + 4096;
  unsigned short* const lv0 = lds + 8192;
  unsigned short* const lv1 = lds + 16384;
  unsigned short* const lp  = lds + 24576;

  // XCD-locality mapping: all 16 blocks of a bh on one XCD (wgid%8 round-robin)
  int lin = blockIdx.x;            // 0..511
  int xcd = lin & 7, slot = lin >> 3;       // slot 0..63
  int bh = xcd + 8 * (slot >> 4);           // 4 bh per XCD
  int bx = slot & 15;                       // pair index
  int b = bh >> 4, h = bh & 15;
  float decay = __logf(1.f - exp2f(-5.f - (float)h));
  int tid = threadIdx.x, wave = tid >> 6, lane = tid & 63;
  int lr = lane & 15, lg = lane >> 4;
  const unsigned short* qbase = &qr[(size_t)bh * 2048 * 64];
  const unsigned short* kbase = &kr[(size_t)bh * 2048 * 64];
  const unsigned short* vbase = &vT[(size_t)bh * 128 * 2048];
  unsigned short* lpw = &lp[wave * 16 * LPAD];
  int swz = (lr & 7) << 3;                  // read-side XOR swizzle (shorts)

  float cf[4][4];
#pragma unroll
  for (int nb = 0; nb < 4; nb++)
#pragma unroll
    for (int r = 0; r < 4; r++)
      cf[nb][r] = __expf(-decay * (float)(nb * 16 + lg * 4 + r));

  auto stage = [&](int bufi, int t0) {
    const char* kg = (const char*)(kbase + (size_t)t0 * 64);   // contiguous 8KB
    const char* vg = (const char*)vbase + (size_t)t0 * 2;
    char* lk = (char*)(bufi ? lk1 : lk0);
    char* lv = (char*)(bufi ? lv1 : lv0);
#pragma unroll
    for (int i = 0; i < 2; i++) {
      int c = tid + i * 256;                 // 512 chunks of 16B
      int r = c >> 3, j = c & 7;
      gload16(kg + r * 128 + ((j ^ (r & 7)) << 4), lk + c * 16);
    }
#pragma unroll
    for (int i = 0; i < 4; i++) {
      int c = tid + i * 256;                 // 1024 chunks of 16B
      int d = c >> 3, j = c & 7;
      gload16(vg + (size_t)d * 4096 + ((j ^ (d & 7)) << 4), lv + c * 16);
    }
  };

  for (int pass = 0; pass < 2; pass++) {
    int stile = pass ? 31 - bx : bx;
    int s0 = stile * 64;
    int sq = s0 + wave * 16 + lr;            // this lane's q-row
    bf16x8 qf0 = *(const bf16x8*)&qbase[(size_t)sq * 64 + lg * 8];
    bf16x8 qf1 = *(const bf16x8*)&qbase[(size_t)sq * 64 + 32 + lg * 8];
    f32x4 accv[8] = {};
    float rs = 0.f;
    int nt = stile + 1;

    stage(0, 0);
    __syncthreads();
    for (int it = 0; it < nt; it++) {
      int t0 = it * 64;
      if (it + 1 < nt) stage((it + 1) & 1, t0 + 64);   // overlap with compute
      const unsigned short* lk = (it & 1) ? lk1 : lk0;
      const unsigned short* lv = (it & 1) ? lv1 : lv0;
      bool bnd = (it == nt - 1);
      float rowf = __expf(decay * (float)(sq - t0));
#pragma unroll
      for (int nb = 0; nb < 4; nb++) {
        f32x4 sa = {};
        bf16x8 a0 = *(const bf16x8*)&lk[((nb * 16 + lr) * 64 + lg * 8) ^ swz];
        bf16x8 a1 = *(const bf16x8*)&lk[((nb * 16 + lr) * 64 + 32 + lg * 8) ^ swz];
        sa = mfma16(a0, qf0, sa);            // S^T[t][q]
        sa = mfma16(a1, qf1, sa);
        float pv[4];
#pragma unroll
        for (int r = 0; r < 4; r++) {
          float w = rowf * cf[nb][r];
          if (bnd) {
            int tt = t0 + nb * 16 + lg * 4 + r;
            w = (tt <= sq) ? w : 0.f;
          }
          pv[r] = sa[r] * w;
          rs += pv[r];
        }
        unsigned w0 = (unsigned)f2bf(pv[0]) | ((unsigned)f2bf(pv[1]) << 16);
        unsigned w1 = (unsigned)f2bf(pv[2]) | ((unsigned)f2bf(pv[3]) << 16);
        uint2 wv; wv.x = w0; wv.y = w1;
        *(uint2*)&lpw[lr * LPAD + nb * 16 + lg * 4] = wv;   // P[q][t]
      }
#pragma unroll
      for (int kk = 0; kk < 2; kk++) {
        bf16x8 pa = *(const bf16x8*)&lpw[lr * LPAD + kk * 32 + lg * 8];
#pragma unroll
        for (int nb = 0; nb < 8; nb++) {
          bf16x8 bv = *(const bf16x8*)&lv[((nb * 16 + lr) * 64 + kk * 32 + lg * 8) ^ swz];
          accv[nb] = mfma16(pa, bv, accv[nb]);
        }
      }
      __syncthreads();                       // drains next-tile DMA + frees bufs
    }

    // epilogue: rowsum reduce over lg groups (q-row = lr within wave)
    rs += __shfl_xor(rs, 16);
    rs += __shfl_xor(rs, 32);
    int srb = s0 + wave * 16 + lg * 4;
    const unsigned short* gb2 = &Yg[((size_t)(b * 2048 + srb)) * 6144 + 4096 + h * 128];
    unsigned short* zb = &Z[((size_t)(b * 2048 + srb)) * 2048 + h * 128];
#pragma unroll
    for (int r = 0; r < 4; r++) {
      float rsq = __shfl(rs, lg * 4 + r);
      float sidx = (float)(srb + r);
      float geo = (1.f - __expf(decay * (sidx + 1.f))) * exp2f(5.f + (float)h);
      float invs = rsqrtf(geo);
      float den = fmaxf(fabsf(rsq * invs), 1.f);
      float scl = invs / den;
      float sm = 0.f, sq2 = 0.f;
#pragma unroll
      for (int nb = 0; nb < 8; nb++) {
        float v = accv[nb][r] * scl;
        sm += v; sq2 += v * v;
      }
      sm += __shfl_xor(sm, 1); sm += __shfl_xor(sm, 2);
      sm += __shfl_xor(sm, 4); sm += __shfl_xor(sm, 8);
      sq2 += __shfl_xor(sq2, 1); sq2 += __shfl_xor(sq2, 2);
      sq2 += __shfl_xor(sq2, 4); sq2 += __shfl_xor(sq2, 8);
      float mu = sm * (1.f / 128.f);
      float var = sq2 * (1.f / 128.f) - mu * mu;
      float istd = rsqrtf(var + 1e-5f);
#pragma unroll
      for (int nb = 0; nb < 8; nb++) {
        float v = accv[nb][r] * scl;
        float nrm = (v - mu) * istd;
        float g = bf2f(gb2[(size_t)r * 6144 + nb * 16 + lr]);
        float sg = g / (1.f + __expf(-g));
        zb[(size_t)r * 2048 + nb * 16 + lr] = f2bf(nrm * sg);
      }
    }
  }
}

extern "C" void kernel_launch(void* const* d_in, const int* in_sizes, int n_in,
                              void* d_out, int out_size, void* d_ws, size_t ws_size,
                              hipStream_t stream) {
  const float* x  = (const float*)d_in[0];
  const float* Wq = (const float*)d_in[1];
  const float* bq = (const float*)d_in[2];
  const float* Wk = (const float*)d_in[3];
  const float* bk = (const float*)d_in[4];
  const float* Wv = (const float*)d_in[5];
  const float* bv = (const float*)d_in[6];
  const float* Wg = (const float*)d_in[7];
  const float* bg = (const float*)d_in[8];
  const float* Wo = (const float*)d_in[9];
  const float* bo = (const float*)d_in[10];

  char* ws = (char*)d_ws;
  unsigned short* xbf   = (unsigned short*)(ws);                 // [4096][1024]    8.4 MB
  unsigned short* wcatT = (unsigned short*)(ws + 8388608);       // [6144][1024]   12.6 MB
  unsigned short* woT   = (unsigned short*)(ws + 20971520);      // [1024][2048]    4.2 MB
  unsigned short* Y     = (unsigned short*)(ws + 25165824);      // [4096][6144]   50.3 MB
  unsigned short* qrb   = (unsigned short*)(ws + 75497472);      // [32][2048][64]  8.4 MB
  unsigned short* krb   = (unsigned short*)(ws + 83886080);      // [32][2048][64]  8.4 MB
  unsigned short* vT    = (unsigned short*)(ws + 92274688);      // [32][128][2048] 16.8 MB
  float*          bcat  = (float*)(ws + 109051904);              // [6144]
  unsigned short* Z     = xbf;   // aliases xbf+wcatT (16.8 MB), both dead after GEMM1

  // weights -> transposed bf16
  transpose_cast<<<dim3(16, 16), 256, 0, stream>>>(Wq, wcatT, 1024, 1024, 1024, 0);
  transpose_cast<<<dim3(16, 16), 256, 0, stream>>>(Wk, wcatT, 1024, 1024, 1024, 1024);
  transpose_cast<<<dim3(32, 16), 256, 0, stream>>>(Wv, wcatT, 1024, 2048, 1024, 2048);
  transpose_cast<<<dim3(32, 16), 256, 0, stream>>>(Wg, wcatT, 1024, 2048, 1024, 4096);
  transpose_cast<<<dim3(16, 32), 256, 0, stream>>>(Wo, woT, 2048, 1024, 2048, 0);
  biascat_kernel<<<24, 256, 0, stream>>>(bq, bk, bv, bg, bcat);
  cast_x_kernel<<<4096, 256, 0, stream>>>(x, xbf);

  // fused QKVG projection: Y = x @ [Wq|Wk|Wv|Wg] + bias (bf16 out), 256^2 pipeline
  gemm256_kernel<1><<<dim3(24, 16), 512, 0, stream>>>(xbf, wcatT, bcat, Y, 4096, 6144, 1024);

  // prep: RoPE(q,k), v-transpose
  prep_qk_kernel<<<8192, 256, 0, stream>>>(Y, qrb, krb);
  prep_v_kernel<<<dim3(32, 32), 256, 0, stream>>>(Y, vT);

  // retention + LN + silu gate -> Z (bf16); g read directly from Y
  retention_kernel<<<512, 256, 0, stream>>>(qrb, krb, vT, Y, Z);

  // output projection: out = Z @ Wo + bo (fp32 out)
  gemm_kernel<0, 64><<<dim3(16, 32), 256, 0, stream>>>(Z, woT, bo, d_out, 4096, 1024, 2048);
}

// Round 7
// 202.811 us; speedup vs baseline: 1.1569x; 1.0238x over previous
//
#include <hip/hip_runtime.h>
#include <hip/hip_bf16.h>

typedef __attribute__((ext_vector_type(8))) unsigned short ushort8;
typedef __attribute__((ext_vector_type(4))) float f32x4;
typedef __attribute__((ext_vector_type(8))) __bf16 bf16x8;
typedef unsigned int u32_g __attribute__((address_space(1)));
typedef unsigned int u32_l __attribute__((address_space(3)));

__device__ __forceinline__ float bf2f(unsigned short u) {
  union { unsigned u; float f; } v; v.u = ((unsigned)u) << 16; return v.f;
}
__device__ __forceinline__ unsigned short f2bf(float f) {
  union { float f; unsigned u; } v; v.f = f;
  unsigned r = v.u + 0x7FFFu + ((v.u >> 16) & 1u);
  return (unsigned short)(r >> 16);
}
__device__ __forceinline__ f32x4 mfma16(bf16x8 a, bf16x8 b, f32x4 c) {
  return __builtin_amdgcn_mfma_f32_16x16x32_bf16(a, b, c, 0, 0, 0);
}
__device__ __forceinline__ void gload16(const void* g, void* l) {
  __builtin_amdgcn_global_load_lds((const u32_g*)g, (u32_l*)l, 16, 0, 0);
}

// ---------------- weight transpose+cast: W[K][N] fp32 -> WT[row_off+n][k] bf16
__global__ __launch_bounds__(256) void transpose_cast(
    const float* __restrict__ W, unsigned short* __restrict__ WT,
    int K, int N, int ldwt, int row_off)
{
  __shared__ unsigned short t[64 * 80];
  int n0 = blockIdx.x * 64, k0 = blockIdx.y * 64;
  int tid = threadIdx.x;
#pragma unroll
  for (int i = 0; i < 4; i++) {
    int c = tid + 256 * i;
    int r = c >> 4, q = c & 15;
    float4 v = *(const float4*)&W[(size_t)(k0 + r) * N + n0 + q * 4];
    t[(q * 4 + 0) * 80 + r] = f2bf(v.x);
    t[(q * 4 + 1) * 80 + r] = f2bf(v.y);
    t[(q * 4 + 2) * 80 + r] = f2bf(v.z);
    t[(q * 4 + 3) * 80 + r] = f2bf(v.w);
  }
  __syncthreads();
#pragma unroll
  for (int i = 0; i < 2; i++) {
    int c = tid + 256 * i;
    int n = c >> 3, p = c & 7;
    *(ushort8*)&WT[(size_t)(row_off + n0 + n) * ldwt + k0 + p * 8] =
        *(const ushort8*)&t[n * 80 + p * 8];
  }
}

__global__ void biascat_kernel(const float* __restrict__ bq, const float* __restrict__ bk,
                               const float* __restrict__ bv, const float* __restrict__ bg,
                               float* __restrict__ bcat)
{
  int i = blockIdx.x * 256 + threadIdx.x;   // 6144
  float v;
  if (i < 1024) v = bq[i];
  else if (i < 2048) v = bk[i - 1024];
  else if (i < 4096) v = bv[i - 2048];
  else v = bg[i - 4096];
  bcat[i] = v;
}

__global__ void cast_x_kernel(const float* __restrict__ x, unsigned short* __restrict__ xb)
{
  size_t i = (size_t)(blockIdx.x * 256 + threadIdx.x) * 4;
  float4 v = *(const float4*)&x[i];
  unsigned r0 = (unsigned)f2bf(v.x) | ((unsigned)f2bf(v.y) << 16);
  unsigned r1 = (unsigned)f2bf(v.z) | ((unsigned)f2bf(v.w) << 16);
  uint2 o; o.x = r0; o.y = r1;
  *(uint2*)&xb[i] = o;
}

// ---------------- GEMM-256: 256x256 tile, 1 barrier/K-tile, m201 wave geometry
// 512 thr = 8 waves (2M x 4N), per-wave 128x64 output, acc[8][4].
// LDS 128KB: 2 buf x (A[256][64] + B[256][64]), both-sides XOR swizzle.
// Per K-tile: vmcnt(0)+barrier -> stage(next, 8 loads/thr) -> 24 ds_read : 64 MFMA,
// A-frag reads software-pipelined one m-pair ahead, setprio around MFMA clusters.
template<int OUT_BF16>
__global__ __launch_bounds__(512, 1) void gemm256_kernel(
    const unsigned short* __restrict__ A, const unsigned short* __restrict__ BT,
    const float* __restrict__ bias, void* __restrict__ Cout,
    int M, int N, int K)
{
  __shared__ __attribute__((aligned(16))) unsigned short lds[65536]; // 128 KiB
  int tid = threadIdx.x, wave = tid >> 6, lane = tid & 63;
  int lr = lane & 15, lg = lane >> 4;
  int gx = gridDim.x;
  int lin = blockIdx.x + gx * blockIdx.y;
  int cpx = (gx * gridDim.y) >> 3;              // nwg % 8 == 0
  int lin2 = (lin & 7) * cpx + (lin >> 3);
  int m0 = (lin2 / gx) * 256, n0 = (lin2 % gx) * 256;
  int wr = (wave >> 2) * 128, wc = (wave & 3) * 64;
  int rsw = lr & 7;

  // per-thread staging sources (pre-swizzled): 4 A chunks + 4 B chunks of 16B
  const unsigned short* gA[4];
  const unsigned short* gB[4];
#pragma unroll
  for (int i = 0; i < 4; i++) {
    int c = tid + i * 512, r = c >> 3, j = c & 7;
    int sw = (j ^ (r & 7)) << 3;
    gA[i] = A  + (size_t)(m0 + r) * K + sw;
    gB[i] = BT + (size_t)(n0 + r) * K + sw;
  }

  auto stage = [&](int buf, int kt) {
    char* la = (char*)lds + buf * 65536;        // bytes
    char* lb = la + 32768;
#pragma unroll
    for (int i = 0; i < 4; i++)
      gload16(gA[i] + kt * 64, la + tid * 16 + i * 8192);
#pragma unroll
    for (int i = 0; i < 4; i++)
      gload16(gB[i] + kt * 64, lb + tid * 16 + i * 8192);
  };

  f32x4 acc[8][4] = {};
  int nk = K >> 6;
  stage(0, 0);
  for (int kt = 0; kt < nk; kt++) {
    int cur = kt & 1;
    const unsigned short* as = lds + cur * 32768;
    const unsigned short* bs = as + 16384;
    asm volatile("s_waitcnt vmcnt(0) lgkmcnt(0)" ::: "memory");
    __builtin_amdgcn_s_barrier();
    __builtin_amdgcn_sched_barrier(0);
    if (kt + 1 < nk) stage(cur ^ 1, kt + 1);
    // B fragments: 8 reads, reused by all 4 m-pairs
    bf16x8 bfr[2][4];
#pragma unroll
    for (int kk = 0; kk < 2; kk++)
#pragma unroll
      for (int n = 0; n < 4; n++)
        bfr[kk][n] = *(const bf16x8*)&bs[(wc + n * 16 + lr) * 64 + (((kk * 4 + lg) ^ rsw) << 3)];
    // A fragments for m-pair 0
    bf16x8 a0[2], a1[2];
#pragma unroll
    for (int kk = 0; kk < 2; kk++) {
      a0[kk] = *(const bf16x8*)&as[(wr + 0 * 16 + lr) * 64 + (((kk * 4 + lg) ^ rsw) << 3)];
      a1[kk] = *(const bf16x8*)&as[(wr + 1 * 16 + lr) * 64 + (((kk * 4 + lg) ^ rsw) << 3)];
    }
#pragma unroll
    for (int mp = 0; mp < 4; mp++) {
      bf16x8 nx0[2], nx1[2];
      if (mp < 3) {
#pragma unroll
        for (int kk = 0; kk < 2; kk++) {
          nx0[kk] = *(const bf16x8*)&as[(wr + (mp * 2 + 2) * 16 + lr) * 64 + (((kk * 4 + lg) ^ rsw) << 3)];
          nx1[kk] = *(const bf16x8*)&as[(wr + (mp * 2 + 3) * 16 + lr) * 64 + (((kk * 4 + lg) ^ rsw) << 3)];
        }
      }
      __builtin_amdgcn_s_setprio(1);
#pragma unroll
      for (int kk = 0; kk < 2; kk++)
#pragma unroll
        for (int n = 0; n < 4; n++) {
          acc[mp * 2 + 0][n] = mfma16(a0[kk], bfr[kk][n], acc[mp * 2 + 0][n]);
          acc[mp * 2 + 1][n] = mfma16(a1[kk], bfr[kk][n], acc[mp * 2 + 1][n]);
        }
      __builtin_amdgcn_s_setprio(0);
      if (mp < 3) {
#pragma unroll
        for (int kk = 0; kk < 2; kk++) { a0[kk] = nx0[kk]; a1[kk] = nx1[kk]; }
      }
    }
  }

#pragma unroll
  for (int m = 0; m < 8; m++) {
#pragma unroll
    for (int n = 0; n < 4; n++) {
      int col = n0 + wc + n * 16 + lr;
      float bv = bias ? bias[col] : 0.f;
#pragma unroll
      for (int r = 0; r < 4; r++) {
        int row = m0 + wr + m * 16 + lg * 4 + r;
        float v = acc[m][n][r] + bv;
        if (OUT_BF16)
          ((unsigned short*)Cout)[(size_t)row * N + col] = f2bf(v);
        else
          ((float*)Cout)[(size_t)row * N + col] = v;
      }
    }
  }
}

// ---------------- GEMM (128-tile, dbuf, swizzled) for the output projection
template<int OUT_BF16, int BN>
__global__ __launch_bounds__(256, 2) void gemm_kernel(
    const unsigned short* __restrict__ A, const unsigned short* __restrict__ BT,
    const float* __restrict__ bias, void* __restrict__ Cout,
    int M, int N, int K)
{
  __shared__ unsigned short As[2 * 128 * 64];
  __shared__ unsigned short Bs[2 * BN * 64];
  constexpr int NR = BN / 32;
  int tid = threadIdx.x;
  int wave = tid >> 6, lane = tid & 63;
  int lr = lane & 15, lg = lane >> 4;
  int gx = gridDim.x;
  int lin = blockIdx.x + gx * blockIdx.y;
  int cpx = (gx * gridDim.y) >> 3;
  int lin2 = (lin & 7) * cpx + (lin >> 3);
  int m0 = (lin2 / gx) * 128, n0 = (lin2 % gx) * BN;
  int wr = (wave >> 1) * 64, wc = (wave & 1) * (BN / 2);
  int srow = tid >> 3, sc8 = tid & 7;
  int ssw = (sc8 ^ (srow & 7)) * 8;
  const unsigned short* ga = &A[(size_t)(m0 + srow) * K + ssw];
  const unsigned short* gb = &BT[(size_t)(n0 + srow) * K + ssw];
  int rsw = lr & 7;
  f32x4 acc[4][NR] = {};

  auto stage = [&](int buf, int k0) {
    char* la = (char*)&As[buf * 128 * 64];
    char* lb = (char*)&Bs[buf * BN * 64];
#pragma unroll
    for (int i = 0; i < 4; i++)
      gload16(ga + (size_t)i * 32 * K + k0, la + (tid + i * 256) * 16);
#pragma unroll
    for (int i = 0; i < NR; i++)
      gload16(gb + (size_t)i * 32 * K + k0, lb + (tid + i * 256) * 16);
  };

  int nk = K >> 6;
  stage(0, 0);
  for (int it = 0; it < nk; it++) {
    __syncthreads();
    if (it + 1 < nk) stage((it + 1) & 1, (it + 1) * 64);
    const unsigned short* as = &As[(it & 1) * 128 * 64];
    const unsigned short* bs = &Bs[(it & 1) * BN * 64];
#pragma unroll
    for (int kk = 0; kk < 2; kk++) {
      int csw = ((kk * 4 + lg) ^ rsw) * 8;
      bf16x8 af[4], bfr[NR];
#pragma unroll
      for (int m = 0; m < 4; m++)
        af[m] = *(const bf16x8*)&as[(wr + m * 16 + lr) * 64 + csw];
#pragma unroll
      for (int n = 0; n < NR; n++)
        bfr[n] = *(const bf16x8*)&bs[(wc + n * 16 + lr) * 64 + csw];
#pragma unroll
      for (int m = 0; m < 4; m++)
#pragma unroll
        for (int n = 0; n < NR; n++)
          acc[m][n] = mfma16(af[m], bfr[n], acc[m][n]);
    }
  }
#pragma unroll
  for (int m = 0; m < 4; m++) {
#pragma unroll
    for (int n = 0; n < NR; n++) {
      int col = n0 + wc + n * 16 + lr;
      float bv = bias ? bias[col] : 0.f;
#pragma unroll
      for (int r = 0; r < 4; r++) {
        int row = m0 + wr + m * 16 + lg * 4 + r;
        float v = acc[m][n][r] + bv;
        if (OUT_BF16)
          ((unsigned short*)Cout)[(size_t)row * N + col] = f2bf(v);
        else
          ((float*)Cout)[(size_t)row * N + col] = v;
      }
    }
  }
}

// ---------------- prep: RoPE for q,k -> [BH][S][64] bf16
__global__ __launch_bounds__(256) void prep_qk_kernel(
    const unsigned short* __restrict__ Y,
    unsigned short* __restrict__ qr, unsigned short* __restrict__ kr)
{
  int t = blockIdx.x * 256 + threadIdx.x;  // [bs:4096][h:16][j:32]
  int j = t & 31;
  int h = (t >> 5) & 15;
  int bs = t >> 9;
  int s = bs & 2047;
  int b = bs >> 11;
  float ang = __expf(-0.29710774f * (float)j);   // 10000^(-j/31)
  float th = (float)s * ang;
  float sn, cs;
  __sincosf(th, &sn, &cs);
  const unsigned short* yq = &Y[(size_t)bs * 6144 + h * 64 + 2 * j];
  unsigned qv = *(const unsigned*)yq;
  unsigned kv = *(const unsigned*)(yq + 1024);
  float q0 = bf2f((unsigned short)(qv & 0xffff));
  float q1 = bf2f((unsigned short)(qv >> 16));
  float k0 = bf2f((unsigned short)(kv & 0xffff)) * 0.125f;
  float k1 = bf2f((unsigned short)(kv >> 16)) * 0.125f;
  float qr0 = q0 * cs - q1 * sn, qr1 = q1 * cs + q0 * sn;
  float kr0 = k0 * cs - k1 * sn, kr1 = k1 * cs + k0 * sn;
  size_t o = ((size_t)(b * 16 + h) * 2048 + s) * 64 + 2 * j;
  *(unsigned*)&qr[o] = (unsigned)f2bf(qr0) | ((unsigned)f2bf(qr1) << 16);
  *(unsigned*)&kr[o] = (unsigned)f2bf(kr0) | ((unsigned)f2bf(kr1) << 16);
}

// ---------------- prep: v transpose -> vT[BH][128][2048] bf16
__global__ __launch_bounds__(256) void prep_v_kernel(
    const unsigned short* __restrict__ Y, unsigned short* __restrict__ vT)
{
  __shared__ unsigned short t[128 * 80];
  int s0 = blockIdx.x * 64;
  int bh = blockIdx.y;
  int b = bh >> 4, h = bh & 15;
  int tid = threadIdx.x;
#pragma unroll
  for (int i = 0; i < 4; i++) {
    int c = tid + 256 * i;
    int r = c >> 4, p = c & 15;
    ushort8 v = *(const ushort8*)&Y[(size_t)(b * 2048 + s0 + r) * 6144 + 2048 + h * 128 + p * 8];
#pragma unroll
    for (int e = 0; e < 8; e++) t[(p * 8 + e) * 80 + r] = v[e];
  }
  __syncthreads();
#pragma unroll
  for (int i = 0; i < 4; i++) {
    int c = tid + 256 * i;
    int d = c >> 3, p = c & 7;
    *(ushort8*)&vT[((size_t)bh * 128 + d) * 2048 + s0 + p * 8] = *(const ushort8*)&t[d * 80 + p * 8];
  }
}

// ---------------- retention: swapped-QK, XCD-local bh, DMA double-buffered K/V
// (R3 balanced-pair structure: every block does exactly 33 tile-iters)
#define LPAD 72
__global__ __launch_bounds__(256, 2) void retention_kernel(
    const unsigned short* __restrict__ qr, const unsigned short* __restrict__ kr,
    const unsigned short* __restrict__ vT, const unsigned short* __restrict__ Yg,
    unsigned short* __restrict__ Z)
{
  // shorts: kA[4096] kB[4096] vA[8192] vB[8192] lp[4*16*72]
  __shared__ __attribute__((aligned(16))) unsigned short lds[24576 + 4 * 16 * LPAD];
  unsigned short* const lk0 = lds;
  unsigned short* const lk1 = lds + 4096;
  unsigned short* const lv0 = lds + 8192;
  unsigned short* const lv1 = lds + 16384;
  unsigned short* const lp  = lds + 24576;

  // XCD-locality mapping: all 16 blocks of a bh on one XCD (wgid%8 round-robin)
  int lin = blockIdx.x;            // 0..511
  int xcd = lin & 7, slot = lin >> 3;       // slot 0..63
  int bh = xcd + 8 * (slot >> 4);           // 4 bh per XCD
  int bx = slot & 15;                       // pair index
  int b = bh >> 4, h = bh & 15;
  float decay = __logf(1.f - exp2f(-5.f - (float)h));
  int tid = threadIdx.x, wave = tid >> 6, lane = tid & 63;
  int lr = lane & 15, lg = lane >> 4;
  const unsigned short* qbase = &qr[(size_t)bh * 2048 * 64];
  const unsigned short* kbase = &kr[(size_t)bh * 2048 * 64];
  const unsigned short* vbase = &vT[(size_t)bh * 128 * 2048];
  unsigned short* lpw = &lp[wave * 16 * LPAD];
  int swz = (lr & 7) << 3;                  // read-side XOR swizzle (shorts)

  float cf[4][4];
#pragma unroll
  for (int nb = 0; nb < 4; nb++)
#pragma unroll
    for (int r = 0; r < 4; r++)
      cf[nb][r] = __expf(-decay * (float)(nb * 16 + lg * 4 + r));

  auto stage = [&](int bufi, int t0) {
    const char* kg = (const char*)(kbase + (size_t)t0 * 64);   // contiguous 8KB
    const char* vg = (const char*)vbase + (size_t)t0 * 2;
    char* lk = (char*)(bufi ? lk1 : lk0);
    char* lv = (char*)(bufi ? lv1 : lv0);
#pragma unroll
    for (int i = 0; i < 2; i++) {
      int c = tid + i * 256;                 // 512 chunks of 16B
      int r = c >> 3, j = c & 7;
      gload16(kg + r * 128 + ((j ^ (r & 7)) << 4), lk + c * 16);
    }
#pragma unroll
    for (int i = 0; i < 4; i++) {
      int c = tid + i * 256;                 // 1024 chunks of 16B
      int d = c >> 3, j = c & 7;
      gload16(vg + (size_t)d * 4096 + ((j ^ (d & 7)) << 4), lv + c * 16);
    }
  };

  for (int pass = 0; pass < 2; pass++) {
    int stile = pass ? 31 - bx : bx;
    int s0 = stile * 64;
    int sq = s0 + wave * 16 + lr;            // this lane's q-row
    bf16x8 qf0 = *(const bf16x8*)&qbase[(size_t)sq * 64 + lg * 8];
    bf16x8 qf1 = *(const bf16x8*)&qbase[(size_t)sq * 64 + 32 + lg * 8];
    f32x4 accv[8] = {};
    float rs = 0.f;
    int nt = stile + 1;

    stage(0, 0);
    __syncthreads();
    for (int it = 0; it < nt; it++) {
      int t0 = it * 64;
      if (it + 1 < nt) stage((it + 1) & 1, t0 + 64);   // overlap with compute
      const unsigned short* lk = (it & 1) ? lk1 : lk0;
      const unsigned short* lv = (it & 1) ? lv1 : lv0;
      bool bnd = (it == nt - 1);
      float rowf = __expf(decay * (float)(sq - t0));
#pragma unroll
      for (int nb = 0; nb < 4; nb++) {
        f32x4 sa = {};
        bf16x8 a0 = *(const bf16x8*)&lk[((nb * 16 + lr) * 64 + lg * 8) ^ swz];
        bf16x8 a1 = *(const bf16x8*)&lk[((nb * 16 + lr) * 64 + 32 + lg * 8) ^ swz];
        sa = mfma16(a0, qf0, sa);            // S^T[t][q]
        sa = mfma16(a1, qf1, sa);
        float pv[4];
#pragma unroll
        for (int r = 0; r < 4; r++) {
          float w = rowf * cf[nb][r];
          if (bnd) {
            int tt = t0 + nb * 16 + lg * 4 + r;
            w = (tt <= sq) ? w : 0.f;
          }
          pv[r] = sa[r] * w;
          rs += pv[r];
        }
        unsigned w0 = (unsigned)f2bf(pv[0]) | ((unsigned)f2bf(pv[1]) << 16);
        unsigned w1 = (unsigned)f2bf(pv[2]) | ((unsigned)f2bf(pv[3]) << 16);
        uint2 wv; wv.x = w0; wv.y = w1;
        *(uint2*)&lpw[lr * LPAD + nb * 16 + lg * 4] = wv;   // P[q][t]
      }
#pragma unroll
      for (int kk = 0; kk < 2; kk++) {
        bf16x8 pa = *(const bf16x8*)&lpw[lr * LPAD + kk * 32 + lg * 8];
#pragma unroll
        for (int nb = 0; nb < 8; nb++) {
          bf16x8 bv = *(const bf16x8*)&lv[((nb * 16 + lr) * 64 + kk * 32 + lg * 8) ^ swz];
          accv[nb] = mfma16(pa, bv, accv[nb]);
        }
      }
      __syncthreads();                       // drains next-tile DMA + frees bufs
    }

    // epilogue: rowsum reduce over lg groups (q-row = lr within wave)
    rs += __shfl_xor(rs, 16);
    rs += __shfl_xor(rs, 32);
    int srb = s0 + wave * 16 + lg * 4;
    const unsigned short* gb2 = &Yg[((size_t)(b * 2048 + srb)) * 6144 + 4096 + h * 128];
    unsigned short* zb = &Z[((size_t)(b * 2048 + srb)) * 2048 + h * 128];
#pragma unroll
    for (int r = 0; r < 4; r++) {
      float rsq = __shfl(rs, lg * 4 + r);
      float sidx = (float)(srb + r);
      float geo = (1.f - __expf(decay * (sidx + 1.f))) * exp2f(5.f + (float)h);
      float invs = rsqrtf(geo);
      float den = fmaxf(fabsf(rsq * invs), 1.f);
      float scl = invs / den;
      float sm = 0.f, sq2 = 0.f;
#pragma unroll
      for (int nb = 0; nb < 8; nb++) {
        float v = accv[nb][r] * scl;
        sm += v; sq2 += v * v;
      }
      sm += __shfl_xor(sm, 1); sm += __shfl_xor(sm, 2);
      sm += __shfl_xor(sm, 4); sm += __shfl_xor(sm, 8);
      sq2 += __shfl_xor(sq2, 1); sq2 += __shfl_xor(sq2, 2);
      sq2 += __shfl_xor(sq2, 4); sq2 += __shfl_xor(sq2, 8);
      float mu = sm * (1.f / 128.f);
      float var = sq2 * (1.f / 128.f) - mu * mu;
      float istd = rsqrtf(var + 1e-5f);
#pragma unroll
      for (int nb = 0; nb < 8; nb++) {
        float v = accv[nb][r] * scl;
        float nrm = (v - mu) * istd;
        float g = bf2f(gb2[(size_t)r * 6144 + nb * 16 + lr]);
        float sg = g / (1.f + __expf(-g));
        zb[(size_t)r * 2048 + nb * 16 + lr] = f2bf(nrm * sg);
      }
    }
  }
}

extern "C" void kernel_launch(void* const* d_in, const int* in_sizes, int n_in,
                              void* d_out, int out_size, void* d_ws, size_t ws_size,
                              hipStream_t stream) {
  const float* x  = (const float*)d_in[0];
  const float* Wq = (const float*)d_in[1];
  const float* bq = (const float*)d_in[2];
  const float* Wk = (const float*)d_in[3];
  const float* bk = (const float*)d_in[4];
  const float* Wv = (const float*)d_in[5];
  const float* bv = (const float*)d_in[6];
  const float* Wg = (const float*)d_in[7];
  const float* bg = (const float*)d_in[8];
  const float* Wo = (const float*)d_in[9];
  const float* bo = (const float*)d_in[10];

  char* ws = (char*)d_ws;
  unsigned short* xbf   = (unsigned short*)(ws);                 // [4096][1024]    8.4 MB
  unsigned short* wcatT = (unsigned short*)(ws + 8388608);       // [6144][1024]   12.6 MB
  unsigned short* woT   = (unsigned short*)(ws + 20971520);      // [1024][2048]    4.2 MB
  unsigned short* Y     = (unsigned short*)(ws + 25165824);      // [4096][6144]   50.3 MB
  unsigned short* qrb   = (unsigned short*)(ws + 75497472);      // [32][2048][64]  8.4 MB
  unsigned short* krb   = (unsigned short*)(ws + 83886080);      // [32][2048][64]  8.4 MB
  unsigned short* vT    = (unsigned short*)(ws + 92274688);      // [32][128][2048] 16.8 MB
  float*          bcat  = (float*)(ws + 109051904);              // [6144]
  unsigned short* Z     = xbf;   // aliases xbf+wcatT (16.8 MB), both dead after GEMM1

  // weights -> transposed bf16
  transpose_cast<<<dim3(16, 16), 256, 0, stream>>>(Wq, wcatT, 1024, 1024, 1024, 0);
  transpose_cast<<<dim3(16, 16), 256, 0, stream>>>(Wk, wcatT, 1024, 1024, 1024, 1024);
  transpose_cast<<<dim3(32, 16), 256, 0, stream>>>(Wv, wcatT, 1024, 2048, 1024, 2048);
  transpose_cast<<<dim3(32, 16), 256, 0, stream>>>(Wg, wcatT, 1024, 2048, 1024, 4096);
  transpose_cast<<<dim3(16, 32), 256, 0, stream>>>(Wo, woT, 2048, 1024, 2048, 0);
  biascat_kernel<<<24, 256, 0, stream>>>(bq, bk, bv, bg, bcat);
  cast_x_kernel<<<4096, 256, 0, stream>>>(x, xbf);

  // fused QKVG projection: Y = x @ [Wq|Wk|Wv|Wg] + bias (bf16 out), 256^2 pipeline
  gemm256_kernel<1><<<dim3(24, 16), 512, 0, stream>>>(xbf, wcatT, bcat, Y, 4096, 6144, 1024);

  // prep: RoPE(q,k), v-transpose
  prep_qk_kernel<<<8192, 256, 0, stream>>>(Y, qrb, krb);
  prep_v_kernel<<<dim3(32, 32), 256, 0, stream>>>(Y, vT);

  // retention + LN + silu gate -> Z (bf16); g read directly from Y
  retention_kernel<<<512, 256, 0, stream>>>(qrb, krb, vT, Y, Z);

  // output projection: out = Z @ Wo + bo (fp32 out)
  gemm_kernel<0, 64><<<dim3(16, 32), 256, 0, stream>>>(Z, woT, bo, d_out, 4096, 1024, 2048);
}